// Round 15
// baseline (119.834 us; speedup 1.0000x reference)
//
#include <hip/hip_runtime.h>

// VQ quantizer: z [8,8,16,64,64] f32, codebook [512,8] f32
// outputs concat: z_q_st (4194304 f32) | vq_loss (1 f32) | idx (524288 f32-valued)
//
// R15 = R14 (58.6us kernel) with the prep kernel MERGED into vq_main:
//  - each block self-builds B fragments from cb directly into LDS (identical
//    formulas -> identical bits); no global wsB round-trip, no prep node.
//  - quad2 rows (eh, multiplied by -2zl) duplicate quad0's eh -> quad2 lanes
//    read quad0's LDS slot (same-address broadcast, free). ldsB 32->24 KB.
//  - phase C computes e2 inline: np_sumsq8 of the cb row it already loads
//    (bit-identical to the old e2f table).
//  - out_loss zeroed via hipMemsetAsync (graph-safe). ONE worker kernel.
// Validated bit-exact pipeline (absmax 0, R6-R14): split-bf16 MFMA filter,
// eps-threshold candidate collection, np-exact rescue. All numerics unchanged.

#define NPTS      524288      // 8*16*64*64
#define KCODES    512
#define DDIM      8
#define CH_STRIDE 65536       // T*H*W
#define B_STRIDE  524288      // D*T*H*W
#define BLK       512
#define NWAVES    8
#define NTILES    32          // 512 codes / 16
#define CMAX      4
#define FLT_BIG   3.402823466e+38f

typedef short bf8 __attribute__((ext_vector_type(8)));   // 8 bf16 (4 VGPRs)
typedef float f4  __attribute__((ext_vector_type(4)));   // fp32 accum

__device__ __forceinline__ unsigned short f2bf(float f) {   // RNE f32->bf16
    unsigned u = __float_as_uint(f);
    unsigned r = u + 0x7fffu + ((u >> 16) & 1u);
    return (unsigned short)(r >> 16);
}
__device__ __forceinline__ float bf2f(unsigned short h) {
    return __uint_as_float(((unsigned)h) << 16);
}

// numpy pairwise-sum tree for n=8 (validated absmax 0, R1-R14)
__device__ __forceinline__ float np_sumsq8(const float* x) {
    float p0 = __fmul_rn(x[0], x[0]);
    float p1 = __fmul_rn(x[1], x[1]);
    float p2 = __fmul_rn(x[2], x[2]);
    float p3 = __fmul_rn(x[3], x[3]);
    float p4 = __fmul_rn(x[4], x[4]);
    float p5 = __fmul_rn(x[5], x[5]);
    float p6 = __fmul_rn(x[6], x[6]);
    float p7 = __fmul_rn(x[7], x[7]);
    return __fadd_rn(__fadd_rn(__fadd_rn(p0, p1), __fadd_rn(p2, p3)),
                     __fadd_rn(__fadd_rn(p4, p5), __fadd_rn(p6, p7)));
}

// np-exact distance; e2 computed inline from the same row (bit-identical to
// the old e2f table: same np_sumsq8 chain). Validated rounding chain.
__device__ __forceinline__ float np_dist_cb(const float* __restrict__ cb,
                                            int k, const float* zv, float z2) {
    const float* c = cb + (size_t)k * DDIM;
    float cr[DDIM];
    #pragma unroll
    for (int j = 0; j < DDIM; ++j) cr[j] = c[j];
    float ze = 0.0f;
    #pragma unroll
    for (int j = 0; j < DDIM; ++j) ze = __fmaf_rn(zv[j], cr[j], ze);
    const float e2 = np_sumsq8(cr);
    return __fmaf_rn(-2.0f, ze, __fadd_rn(z2, e2));
}

__global__ __launch_bounds__(BLK, 4) void vq_main(
    const float* __restrict__ z, const float* __restrict__ cb,
    float* __restrict__ out_zq, float* __restrict__ out_loss,
    float* __restrict__ out_idx)
{
    // ldsB tile layout (48 lane-slots of 8 ushorts each):
    //   slots  0-15: quad0 data (eh[j]) for code col
    //   slots 16-31: quad1 data (el[j])
    //   slots 32-47: quad3 data {e2h, e2l, 0 x6}
    // quad2 readers (need eh again) alias quad0's slot (broadcast, free).
    __shared__ unsigned short ldsB[NTILES * 48 * 8];   // 24 KB
    __shared__ int            ccnt[BLK];               // 2 KB
    __shared__ unsigned short clist[BLK][CMAX];        // 4 KB
    __shared__ float          wsum[NWAVES];

    const int tid  = threadIdx.x;
    const int wave = tid >> 6;
    const int lane = tid & 63;
    const int quad = lane >> 4;
    const int col  = lane & 15;

    // ---- self-build B fragments: thread i handles code i (formulas identical
    //      to the old prep kernel -> identical bits) ----
    {
        const float* row = cb + (size_t)tid * DDIM;
        float rv[DDIM];
        #pragma unroll
        for (int j = 0; j < DDIM; ++j) rv[j] = row[j];
        const float e2 = np_sumsq8(rv);

        unsigned eh2[4], el2[4];
        #pragma unroll
        for (int jj = 0; jj < 4; ++jj) {
            const unsigned short h0 = f2bf(rv[2 * jj]);
            const unsigned short h1 = f2bf(rv[2 * jj + 1]);
            const unsigned short l0 = f2bf(__fsub_rn(rv[2 * jj],     bf2f(h0)));
            const unsigned short l1 = f2bf(__fsub_rn(rv[2 * jj + 1], bf2f(h1)));
            eh2[jj] = (unsigned)h0 | ((unsigned)h1 << 16);
            el2[jj] = (unsigned)l0 | ((unsigned)l1 << 16);
        }
        const unsigned short e2h = f2bf(e2);
        const unsigned short e2l = f2bf(__fsub_rn(e2, bf2f(e2h)));

        const int t = tid >> 4;      // tile
        const int c = tid & 15;      // col within tile
        uint4* base = (uint4*)ldsB;  // 16B per lane-slot
        base[t * 48 + c]      = (uint4){eh2[0], eh2[1], eh2[2], eh2[3]};
        base[t * 48 + 16 + c] = (uint4){el2[0], el2[1], el2[2], el2[3]};
        base[t * 48 + 32 + c] = (uint4){(unsigned)e2h | ((unsigned)e2l << 16), 0u, 0u, 0u};
    }
    ccnt[tid] = 0;

    // lane owns point n: fully coalesced loads (overlaps fragment build)
    const int n = blockIdx.x * BLK + tid;
    const int b = n >> 16;
    const int s = n & 65535;
    const float* zp = z + (size_t)b * B_STRIDE + s;
    float zv[DDIM];
    #pragma unroll
    for (int j = 0; j < DDIM; ++j) zv[j] = zp[(size_t)j * CH_STRIDE];
    const float z2 = np_sumsq8(zv);

    // wave-wide z2 max -> eps (validated constants)
    float zmax = z2;
    #pragma unroll
    for (int mk = 1; mk <= 32; mk <<= 1) zmax = fmaxf(zmax, __shfl_xor(zmax, mk, 64));
    const float eps = zmax * 6e-7f + 3e-6f;

    // pre-pack own point's A-material: lo16 = bf16(-2*zh), hi16 = bf16(-2*zl)
    unsigned pkz[8];
    #pragma unroll
    for (int j = 0; j < 8; ++j) {
        const unsigned short hh = f2bf(zv[j]);
        const float zh = bf2f(hh);
        const float zl = __fsub_rn(zv[j], zh);        // exact
        const unsigned short ah = f2bf(-2.0f * zh);   // exact
        const unsigned short al = f2bf(-2.0f * zl);
        pkz[j] = (unsigned)ah | ((unsigned)al << 16);
    }

    // afrag_q at lane (col,quad): A[m=col][k=quad*8+j] from owner lane q*16+col.
    // quad0/1: -2zh, quad2: -2zl, quad3: {1,1,0..} (validated)
    bf8 af0, af1, af2, af3;
#define MK_AFRAG(AF, Q)                                                        \
    {                                                                          \
        const int srcl = (Q)*16 + col;                                         \
        _Pragma("unroll")                                                      \
        for (int j = 0; j < 8; ++j) {                                          \
            const unsigned w = (unsigned)__shfl((int)pkz[j], srcl, 64);        \
            const unsigned us = (quad == 2) ? (w >> 16) : (w & 0xFFFFu);       \
            AF[j] = (short)us;                                                 \
        }                                                                      \
        if (quad == 3) AF = (bf8){(short)0x3F80, (short)0x3F80, 0, 0, 0, 0, 0, 0}; \
    }
    MK_AFRAG(af0, 0) MK_AFRAG(af1, 1) MK_AFRAG(af2, 2) MK_AFRAG(af3, 3)

    __syncthreads();   // ldsB built by all waves -> needed

    // reader slot: quad2 aliases quad0's slot; quad3 reads slot region 32-47
    const int rl = lane - ((quad == 2) ? 32 : ((quad == 3) ? 16 : 0));
    const bf8* __restrict__ Bp = (const bf8*)ldsB;

    // ---- pass 1: approx min per point (4 ptiles x 4 regs) ----
    f4 mn0 = (f4){FLT_BIG, FLT_BIG, FLT_BIG, FLT_BIG};
    f4 mn1 = mn0, mn2 = mn0, mn3 = mn0;
    #pragma unroll 4
    for (int t = 0; t < NTILES; ++t) {
        const bf8 bfrag = Bp[t * 48 + rl];
        f4 zero = (f4){0.0f, 0.0f, 0.0f, 0.0f};
        const f4 a0 = __builtin_amdgcn_mfma_f32_16x16x32_bf16(af0, bfrag, zero, 0, 0, 0);
        const f4 a1 = __builtin_amdgcn_mfma_f32_16x16x32_bf16(af1, bfrag, zero, 0, 0, 0);
        const f4 a2 = __builtin_amdgcn_mfma_f32_16x16x32_bf16(af2, bfrag, zero, 0, 0, 0);
        const f4 a3 = __builtin_amdgcn_mfma_f32_16x16x32_bf16(af3, bfrag, zero, 0, 0, 0);
        #pragma unroll
        for (int r = 0; r < 4; ++r) {
            mn0[r] = fminf(mn0[r], a0[r]); mn1[r] = fminf(mn1[r], a1[r]);
            mn2[r] = fminf(mn2[r], a2[r]); mn3[r] = fminf(mn3[r], a3[r]);
        }
    }
    // min across the 16 cols (xor bits 0..3), then add eps -> thresholds
    #pragma unroll
    for (int mk = 1; mk <= 8; mk <<= 1) {
        #pragma unroll
        for (int r = 0; r < 4; ++r) {
            mn0[r] = fminf(mn0[r], __shfl_xor(mn0[r], mk, 64));
            mn1[r] = fminf(mn1[r], __shfl_xor(mn1[r], mk, 64));
            mn2[r] = fminf(mn2[r], __shfl_xor(mn2[r], mk, 64));
            mn3[r] = fminf(mn3[r], __shfl_xor(mn3[r], mk, 64));
        }
    }
    #pragma unroll
    for (int r = 0; r < 4; ++r) {
        mn0[r] += eps; mn1[r] += eps; mn2[r] += eps; mn3[r] += eps;
    }

    // ---- pass 2: identical accs; predicated push (rarely taken) ----
    // C layout: point-in-block = wave*64 + Q*16 + quad*4 + r, code = t*16 + col
    const int pbase = wave * 64 + quad * 4;
    #pragma unroll 4
    for (int t = 0; t < NTILES; ++t) {
        const bf8 bfrag = Bp[t * 48 + rl];
        f4 zero = (f4){0.0f, 0.0f, 0.0f, 0.0f};
        const f4 a0 = __builtin_amdgcn_mfma_f32_16x16x32_bf16(af0, bfrag, zero, 0, 0, 0);
        const f4 a1 = __builtin_amdgcn_mfma_f32_16x16x32_bf16(af1, bfrag, zero, 0, 0, 0);
        const f4 a2 = __builtin_amdgcn_mfma_f32_16x16x32_bf16(af2, bfrag, zero, 0, 0, 0);
        const f4 a3 = __builtin_amdgcn_mfma_f32_16x16x32_bf16(af3, bfrag, zero, 0, 0, 0);
        const unsigned short code = (unsigned short)(t * 16 + col);
#define PUSH(AQ, MQ, Q)                                                        \
    {                                                                          \
        const bool c0 = AQ[0] <= MQ[0], c1 = AQ[1] <= MQ[1];                   \
        const bool c2 = AQ[2] <= MQ[2], c3 = AQ[3] <= MQ[3];                   \
        if (c0 | c1 | c2 | c3) {                                               \
            const int pt = pbase + (Q)*16;                                     \
            if (c0) { int p = atomicAdd(&ccnt[pt + 0], 1); if (p < CMAX) clist[pt + 0][p] = code; } \
            if (c1) { int p = atomicAdd(&ccnt[pt + 1], 1); if (p < CMAX) clist[pt + 1][p] = code; } \
            if (c2) { int p = atomicAdd(&ccnt[pt + 2], 1); if (p < CMAX) clist[pt + 2][p] = code; } \
            if (c3) { int p = atomicAdd(&ccnt[pt + 3], 1); if (p < CMAX) clist[pt + 3][p] = code; } \
        }                                                                      \
    }
        PUSH(a0, mn0, 0) PUSH(a1, mn1, 1) PUSH(a2, mn2, 2) PUSH(a3, mn3, 3)
    }

    // ccnt/clist for this wave's 64 points is written and read ONLY by this
    // wave -> no block barrier; drain this wave's LDS ops (writes + atomics).
    asm volatile("s_waitcnt lgkmcnt(0)" ::: "memory");

    // ---- phase C: every lane resolves its own point np-exactly ----
    const int cnt = ccnt[tid];
    int bidx;
    if (cnt == 1) {
        // eps guarantee: candidate set contains np's argmin; singleton => done
        bidx = clist[tid][0];
    } else if (cnt <= CMAX) {
        float best = FLT_BIG; bidx = 0;
        for (int i = 0; i < cnt; ++i) {
            const int k = clist[tid][i];
            const float d = np_dist_cb(cb, k, zv, z2);
            // order-independent np first-min
            if (d < best || (d == best && k < bidx)) { best = d; bidx = k; }
        }
    } else {  // overflow fallback: full exact scan (correctness net)
        float best = FLT_BIG; bidx = 0;
        for (int k = 0; k < KCODES; ++k) {
            const float d = np_dist_cb(cb, k, zv, z2);
            if (d < best) { best = d; bidx = k; }
        }
    }
    out_idx[n] = (float)bidx;

    const float* cw = cb + (size_t)bidx * DDIM;
    float* op = out_zq + (size_t)b * B_STRIDE + s;
    float lsum = 0.0f;
    #pragma unroll
    for (int j = 0; j < DDIM; ++j) {
        const float zq = cw[j];
        const float t  = __fsub_rn(zq, zv[j]);            // np: z_q - z
        op[(size_t)j * CH_STRIDE] = __fadd_rn(zv[j], t);  // np: z + (z_q - z)
        lsum = __fmaf_rn(t, t, lsum);                     // loss (2% tol)
    }

    // loss: wave butterfly -> LDS wsum -> one atomic per BLOCK (validated path)
    #pragma unroll
    for (int off = 32; off > 0; off >>= 1) lsum += __shfl_down(lsum, off, 64);
    if (lane == 0) wsum[wave] = lsum;
    __syncthreads();
    if (tid == 0) {
        float bs = 0.0f;
        #pragma unroll
        for (int w = 0; w < NWAVES; ++w) bs += wsum[w];
        // vq_loss = codebk + BETA*commit = 1.25 * mean((z_q - z)^2)
        atomicAdd(out_loss, bs * (1.25f / 4194304.0f));
    }
}

extern "C" void kernel_launch(void* const* d_in, const int* in_sizes, int n_in,
                              void* d_out, int out_size, void* d_ws, size_t ws_size,
                              hipStream_t stream) {
    const float* z  = (const float*)d_in[0];
    const float* cb = (const float*)d_in[1];
    float* out      = (float*)d_out;
    float* out_zq   = out;                    // 4194304 elems
    float* out_loss = out + 4194304;          // 1 elem
    float* out_idx  = out + 4194305;          // 524288 elems (as float values)

    hipMemsetAsync(out_loss, 0, sizeof(float), stream);
    vq_main<<<NPTS / BLK, BLK, 0, stream>>>(z, cb, out_zq, out_loss, out_idx);
}